// Round 6
// baseline (68.904 us; speedup 1.0000x reference)
//
#include <hip/hip_runtime.h>
#include <hip/hip_bf16.h>

#define D1 8
#define RANK 8
#define ROWS 4   // rows/thread

// fused-multiply-add of one r-slice (8 coeffs in 2 float4s) into 8 accumulators
#define HALF_BLOCK(ACC, SRC, BUF, ROFF)                                   \
    _Pragma("unroll")                                                     \
    for (int r = 0; r < 4; ++r) {                                         \
        _Pragma("unroll")                                                 \
        for (int k = 0; k < ROWS; ++k) {                                  \
            float av = SRC[k][(ROFF) + r];                                \
            ACC[k][0] = fmaf(av, BUF[2*r].x,   ACC[k][0]);                \
            ACC[k][1] = fmaf(av, BUF[2*r].y,   ACC[k][1]);                \
            ACC[k][2] = fmaf(av, BUF[2*r].z,   ACC[k][2]);                \
            ACC[k][3] = fmaf(av, BUF[2*r].w,   ACC[k][3]);                \
            ACC[k][4] = fmaf(av, BUF[2*r+1].x, ACC[k][4]);                \
            ACC[k][5] = fmaf(av, BUF[2*r+1].y, ACC[k][5]);                \
            ACC[k][6] = fmaf(av, BUF[2*r+1].z, ACC[k][6]);                \
            ACC[k][7] = fmaf(av, BUF[2*r+1].w, ACC[k][7]);                \
        }                                                                 \
    }

__global__ __launch_bounds__(256, 2) void tt_poly_kernel(
    const float* __restrict__ X,
    const float* __restrict__ G0,   // [d1, r]
    const float* __restrict__ G1,   // [r, d1, s]
    const float* __restrict__ G2,   // [r, d1, s]
    const float* __restrict__ G3,   // [t, d1]
    float* __restrict__ out,
    int B, int S)
{
    // LDS layouts re-ordered so one d-iteration's coefficients are contiguous:
    // sG1T/sG2T: [d][r][s], sG3T: [d][t], sG0: [d][r] (natural)
    __shared__ float sG0[D1 * RANK];
    __shared__ float sG1T[D1 * RANK * RANK];
    __shared__ float sG2T[D1 * RANK * RANK];
    __shared__ float sG3T[D1 * RANK];

    const int tid = threadIdx.x;
    if (tid < 128) {
        float4 v = reinterpret_cast<const float4*>(G1)[tid];
        int r = tid >> 4, d = (tid >> 1) & 7, h = tid & 1;
        *reinterpret_cast<float4*>(&sG1T[d * 64 + r * 8 + h * 4]) = v;
    } else {
        int i = tid - 128;
        float4 v = reinterpret_cast<const float4*>(G2)[i];
        int r = i >> 4, d = (i >> 1) & 7, h = i & 1;
        *reinterpret_cast<float4*>(&sG2T[d * 64 + r * 8 + h * 4]) = v;
    }
    if (tid < 16)
        reinterpret_cast<float4*>(sG0)[tid] = reinterpret_cast<const float4*>(G0)[tid];
    else if (tid < 80) {
        int i = tid - 16;                 // i = t*8 + d
        sG3T[(i & 7) * RANK + (i >> 3)] = G3[i];
    }
    __syncthreads();

    const int gid = blockIdx.x * blockDim.x + tid;

    float4 x[ROWS];
    #pragma unroll
    for (int k = 0; k < ROWS; ++k) {
        int bb = gid + k * S;
        x[k] = (bb < B) ? reinterpret_cast<const float4*>(X)[bb]
                        : make_float4(0.f, 0.f, 0.f, 0.f);
    }

    float a[ROWS][RANK];
    float b[ROWS][RANK];

    // ---- stage 1: a[k][r] = sum_d x0^d G0[d][r]; full table preloaded to regs ----
    {
        float4 g0v[16];
        #pragma unroll
        for (int j = 0; j < 16; ++j)
            g0v[j] = reinterpret_cast<const float4*>(sG0)[j];
        float xp[ROWS];
        #pragma unroll
        for (int k = 0; k < ROWS; ++k) {
            xp[k] = 1.f;
            #pragma unroll
            for (int r = 0; r < RANK; ++r) a[k][r] = 0.f;
        }
        #pragma unroll
        for (int d = 0; d < D1; ++d) {
            #pragma unroll
            for (int k = 0; k < ROWS; ++k) {
                a[k][0] = fmaf(xp[k], g0v[d*2].x,   a[k][0]);
                a[k][1] = fmaf(xp[k], g0v[d*2].y,   a[k][1]);
                a[k][2] = fmaf(xp[k], g0v[d*2].z,   a[k][2]);
                a[k][3] = fmaf(xp[k], g0v[d*2].w,   a[k][3]);
                a[k][4] = fmaf(xp[k], g0v[d*2+1].x, a[k][4]);
                a[k][5] = fmaf(xp[k], g0v[d*2+1].y, a[k][5]);
                a[k][6] = fmaf(xp[k], g0v[d*2+1].z, a[k][6]);
                a[k][7] = fmaf(xp[k], g0v[d*2+1].w, a[k][7]);
                xp[k] *= x[k].x;
            }
        }
    }

    // ---- stage 2: b = contraction with G1, double-buffered register prefetch ----
    #pragma unroll
    for (int k = 0; k < ROWS; ++k)
        #pragma unroll
        for (int s = 0; s < RANK; ++s) b[k][s] = 0.f;
    {
        const float4* g1v = reinterpret_cast<const float4*>(sG1T);
        float4 bA[8], bB[8];
        #pragma unroll
        for (int j = 0; j < 8; ++j) bA[j] = g1v[j];           // d=0, r 0-3
        #pragma unroll 1
        for (int t = 0; t < D1; ++t) {
            #pragma unroll
            for (int j = 0; j < 8; ++j) bB[j] = g1v[t * 16 + 8 + j];   // d=t, r 4-7
            HALF_BLOCK(b, a, bA, 0)
            if (t < D1 - 1) {
                #pragma unroll
                for (int j = 0; j < 8; ++j) bA[j] = g1v[(t + 1) * 16 + j];
            }
            HALF_BLOCK(b, a, bB, 4)
            if (t < D1 - 1) {
                #pragma unroll
                for (int k = 0; k < ROWS; ++k)
                    #pragma unroll
                    for (int r = 0; r < RANK; ++r) a[k][r] *= x[k].y;
            }
        }
    }

    // ---- stage 3: a = contraction with G2, same pipeline ----
    #pragma unroll
    for (int k = 0; k < ROWS; ++k)
        #pragma unroll
        for (int s = 0; s < RANK; ++s) a[k][s] = 0.f;
    {
        const float4* g2v = reinterpret_cast<const float4*>(sG2T);
        float4 bA[8], bB[8];
        #pragma unroll
        for (int j = 0; j < 8; ++j) bA[j] = g2v[j];
        #pragma unroll 1
        for (int t = 0; t < D1; ++t) {
            #pragma unroll
            for (int j = 0; j < 8; ++j) bB[j] = g2v[t * 16 + 8 + j];
            HALF_BLOCK(a, b, bA, 0)
            if (t < D1 - 1) {
                #pragma unroll
                for (int j = 0; j < 8; ++j) bA[j] = g2v[(t + 1) * 16 + j];
            }
            HALF_BLOCK(a, b, bB, 4)
            if (t < D1 - 1) {
                #pragma unroll
                for (int k = 0; k < ROWS; ++k)
                    #pragma unroll
                    for (int r = 0; r < RANK; ++r) b[k][r] *= x[k].z;
            }
        }
    }

    // ---- stage 4: res[k] = sum_d x3^d (sum_t a[k][t] G3[t][d]); table in regs ----
    float res[ROWS];
    {
        float4 g3v[16];
        #pragma unroll
        for (int j = 0; j < 16; ++j)
            g3v[j] = reinterpret_cast<const float4*>(sG3T)[j];
        float xp[ROWS];
        #pragma unroll
        for (int k = 0; k < ROWS; ++k) { res[k] = 0.f; xp[k] = 1.f; }
        #pragma unroll
        for (int d = 0; d < D1; ++d) {
            #pragma unroll
            for (int k = 0; k < ROWS; ++k) {
                float e;
                e = a[k][0] * g3v[d*2].x;
                e = fmaf(a[k][1], g3v[d*2].y,   e);
                e = fmaf(a[k][2], g3v[d*2].z,   e);
                e = fmaf(a[k][3], g3v[d*2].w,   e);
                e = fmaf(a[k][4], g3v[d*2+1].x, e);
                e = fmaf(a[k][5], g3v[d*2+1].y, e);
                e = fmaf(a[k][6], g3v[d*2+1].z, e);
                e = fmaf(a[k][7], g3v[d*2+1].w, e);
                res[k] = fmaf(e, xp[k], res[k]);
                xp[k] *= x[k].w;
            }
        }
    }

    #pragma unroll
    for (int k = 0; k < ROWS; ++k) {
        int bb = gid + k * S;
        if (bb < B) out[bb] = res[k];
    }
}

extern "C" void kernel_launch(void* const* d_in, const int* in_sizes, int n_in,
                              void* d_out, int out_size, void* d_ws, size_t ws_size,
                              hipStream_t stream) {
    const float* X  = (const float*)d_in[0];
    const float* G0 = (const float*)d_in[1];
    const float* G1 = (const float*)d_in[2];
    const float* G2 = (const float*)d_in[3];
    const float* G3 = (const float*)d_in[4];
    float* out = (float*)d_out;

    int B = in_sizes[0] / 4;   // X is [B,4]
    int block = 256;
    int grid = (B + block * ROWS - 1) / (block * ROWS);
    int S = grid * block;
    tt_poly_kernel<<<grid, block, 0, stream>>>(X, G0, G1, G2, G3, out, B, S);
}

// Round 7
// 58.992 us; speedup vs baseline: 1.1680x; 1.1680x over previous
//
#include <hip/hip_runtime.h>

#define D1 8
#define RANK 8
#define ROWS 4

typedef float v2f __attribute__((ext_vector_type(2)));
typedef float v4f __attribute__((ext_vector_type(4)));

// D (v2f) += broadcast(A.lo) * B      -- per-half src0 select: lo half op_sel[0]=0 -> lo, hi half op_sel_hi[0]=0 -> lo
#define PK_FMA_LO(D, A, B) \
  asm("v_pk_fma_f32 %0, %1, %2, %0 op_sel:[0,0,0] op_sel_hi:[0,1,1]" : "+v"(D) : "v"(A), "v"(B))
// D (v2f) += broadcast(A.hi) * B
#define PK_FMA_HI(D, A, B) \
  asm("v_pk_fma_f32 %0, %1, %2, %0 op_sel:[1,0,0] op_sel_hi:[1,1,1]" : "+v"(D) : "v"(A), "v"(B))
// D += A * B, element-wise
#define PK_FMA(D, A, B) \
  asm("v_pk_fma_f32 %0, %1, %2, %0" : "+v"(D) : "v"(A), "v"(B))
// D *= A, element-wise
#define PK_MUL(D, A) \
  asm("v_pk_mul_f32 %0, %0, %1" : "+v"(D) : "v"(A))

// one 4-row coefficient half-block: ACC2[k][sp] += a-broadcast * gbuf rows
#define HALF_BLOCK_PK(ACC2, SRC2, BUF, RPOFF)                              \
    _Pragma("unroll")                                                      \
    for (int rr = 0; rr < 4; ++rr) {                                       \
        _Pragma("unroll")                                                  \
        for (int k = 0; k < ROWS; ++k) {                                   \
            if ((rr & 1) == 0) {                                           \
                PK_FMA_LO(ACC2[k][0], SRC2[k][(RPOFF) + (rr >> 1)], BUF[2*rr].lo);     \
                PK_FMA_LO(ACC2[k][1], SRC2[k][(RPOFF) + (rr >> 1)], BUF[2*rr].hi);     \
                PK_FMA_LO(ACC2[k][2], SRC2[k][(RPOFF) + (rr >> 1)], BUF[2*rr+1].lo);   \
                PK_FMA_LO(ACC2[k][3], SRC2[k][(RPOFF) + (rr >> 1)], BUF[2*rr+1].hi);   \
            } else {                                                       \
                PK_FMA_HI(ACC2[k][0], SRC2[k][(RPOFF) + (rr >> 1)], BUF[2*rr].lo);     \
                PK_FMA_HI(ACC2[k][1], SRC2[k][(RPOFF) + (rr >> 1)], BUF[2*rr].hi);     \
                PK_FMA_HI(ACC2[k][2], SRC2[k][(RPOFF) + (rr >> 1)], BUF[2*rr+1].lo);   \
                PK_FMA_HI(ACC2[k][3], SRC2[k][(RPOFF) + (rr >> 1)], BUF[2*rr+1].hi);   \
            }                                                              \
        }                                                                  \
    }

__global__ __launch_bounds__(256, 2) void tt_poly_kernel(
    const float* __restrict__ X,
    const float* __restrict__ G0,   // [d1, r]
    const float* __restrict__ G1,   // [r, d1, s]
    const float* __restrict__ G2,   // [r, d1, s]
    const float* __restrict__ G3,   // [t, d1]
    float* __restrict__ out,
    int B, int S)
{
    // LDS: [d][r][s] layout so one d-iteration's 64 coeffs are contiguous
    __shared__ v4f sG0v[16];        // [d][r] natural
    __shared__ v4f sG1Tv[128];      // [d][r][s]
    __shared__ v4f sG2Tv[128];
    __shared__ v4f sG3Tv[16];       // [d][t]

    const int tid = threadIdx.x;
    if (tid < 128) {
        v4f v = reinterpret_cast<const v4f*>(G1)[tid];
        int r = tid >> 4, d = (tid >> 1) & 7, h = tid & 1;
        sG1Tv[d * 16 + r * 2 + h] = v;
    } else {
        int i = tid - 128;
        v4f v = reinterpret_cast<const v4f*>(G2)[i];
        int r = i >> 4, d = (i >> 1) & 7, h = i & 1;
        sG2Tv[d * 16 + r * 2 + h] = v;
    }
    if (tid < 16)
        sG0v[tid] = reinterpret_cast<const v4f*>(G0)[tid];
    else if (tid < 80) {
        int i = tid - 16;                 // i = t*8 + d
        reinterpret_cast<float*>(sG3Tv)[(i & 7) * RANK + (i >> 3)] = G3[i];
    }
    __syncthreads();

    const int gid = blockIdx.x * blockDim.x + tid;

    v4f x[ROWS];
    #pragma unroll
    for (int k = 0; k < ROWS; ++k) {
        int bb = gid + k * S;
        if (bb < B) x[k] = reinterpret_cast<const v4f*>(X)[bb];
        else        x[k] = (v4f){0.f, 0.f, 0.f, 0.f};
    }

    v2f a2[ROWS][4];   // pairs over r
    v2f b2[ROWS][4];
    v2f xpd[ROWS];     // running power, duplicated in both halves

    // ---- stage 1: a[k][r] = sum_d x0^d G0[d][r] ----
    {
        v2f xd[ROWS];
        #pragma unroll
        for (int k = 0; k < ROWS; ++k) {
            xpd[k] = (v2f){1.f, 1.f};
            xd[k]  = (v2f){x[k].x, x[k].x};
            #pragma unroll
            for (int j = 0; j < 4; ++j) a2[k][j] = (v2f){0.f, 0.f};
        }
        #pragma unroll
        for (int d = 0; d < D1; ++d) {
            v4f r0 = sG0v[2 * d], r1 = sG0v[2 * d + 1];
            #pragma unroll
            for (int k = 0; k < ROWS; ++k) {
                PK_FMA(a2[k][0], xpd[k], r0.lo);
                PK_FMA(a2[k][1], xpd[k], r0.hi);
                PK_FMA(a2[k][2], xpd[k], r1.lo);
                PK_FMA(a2[k][3], xpd[k], r1.hi);
                PK_MUL(xpd[k], xd[k]);
            }
        }
    }

    // ---- stage 2: b = contract(a, G1, x1), double-buffered reg prefetch ----
    {
        v2f xyd[ROWS];
        #pragma unroll
        for (int k = 0; k < ROWS; ++k) {
            xyd[k] = (v2f){x[k].y, x[k].y};
            #pragma unroll
            for (int j = 0; j < 4; ++j) b2[k][j] = (v2f){0.f, 0.f};
        }
        const v4f* g = sG1Tv;
        v4f bA[8], bB[8];
        #pragma unroll
        for (int j = 0; j < 8; ++j) bA[j] = g[j];
        #pragma unroll 1
        for (int t = 0; t < D1; ++t) {
            #pragma unroll
            for (int j = 0; j < 8; ++j) bB[j] = g[t * 16 + 8 + j];
            HALF_BLOCK_PK(b2, a2, bA, 0)
            if (t < D1 - 1) {
                #pragma unroll
                for (int j = 0; j < 8; ++j) bA[j] = g[(t + 1) * 16 + j];
            }
            HALF_BLOCK_PK(b2, a2, bB, 2)
            if (t < D1 - 1) {
                #pragma unroll
                for (int k = 0; k < ROWS; ++k)
                    #pragma unroll
                    for (int j = 0; j < 4; ++j) PK_MUL(a2[k][j], xyd[k]);
            }
        }
    }

    // ---- stage 3: a = contract(b, G2, x2) ----
    {
        v2f xzd[ROWS];
        #pragma unroll
        for (int k = 0; k < ROWS; ++k) {
            xzd[k] = (v2f){x[k].z, x[k].z};
            #pragma unroll
            for (int j = 0; j < 4; ++j) a2[k][j] = (v2f){0.f, 0.f};
        }
        const v4f* g = sG2Tv;
        v4f bA[8], bB[8];
        #pragma unroll
        for (int j = 0; j < 8; ++j) bA[j] = g[j];
        #pragma unroll 1
        for (int t = 0; t < D1; ++t) {
            #pragma unroll
            for (int j = 0; j < 8; ++j) bB[j] = g[t * 16 + 8 + j];
            HALF_BLOCK_PK(a2, b2, bA, 0)
            if (t < D1 - 1) {
                #pragma unroll
                for (int j = 0; j < 8; ++j) bA[j] = g[(t + 1) * 16 + j];
            }
            HALF_BLOCK_PK(a2, b2, bB, 2)
            if (t < D1 - 1) {
                #pragma unroll
                for (int k = 0; k < ROWS; ++k)
                    #pragma unroll
                    for (int j = 0; j < 4; ++j) PK_MUL(b2[k][j], xzd[k]);
            }
        }
    }

    // ---- stage 4: res[k] = sum_d x3^d (sum_t a[k][t] G3[t][d]) ----
    v2f res2[ROWS];
    {
        v2f xwd[ROWS];
        #pragma unroll
        for (int k = 0; k < ROWS; ++k) {
            res2[k] = (v2f){0.f, 0.f};
            xpd[k]  = (v2f){1.f, 1.f};
            xwd[k]  = (v2f){x[k].w, x[k].w};
        }
        #pragma unroll
        for (int d = 0; d < D1; ++d) {
            v4f r0 = sG3Tv[2 * d], r1 = sG3Tv[2 * d + 1];
            #pragma unroll
            for (int k = 0; k < ROWS; ++k) {
                v2f e = a2[k][0];
                PK_MUL(e, r0.lo);
                PK_FMA(e, a2[k][1], r0.hi);
                PK_FMA(e, a2[k][2], r1.lo);
                PK_FMA(e, a2[k][3], r1.hi);
                PK_FMA(res2[k], e, xpd[k]);
                PK_MUL(xpd[k], xwd[k]);
            }
        }
    }

    #pragma unroll
    for (int k = 0; k < ROWS; ++k) {
        int bb = gid + k * S;
        if (bb < B) out[bb] = res2[k].x + res2[k].y;
    }
}

extern "C" void kernel_launch(void* const* d_in, const int* in_sizes, int n_in,
                              void* d_out, int out_size, void* d_ws, size_t ws_size,
                              hipStream_t stream) {
    const float* X  = (const float*)d_in[0];
    const float* G0 = (const float*)d_in[1];
    const float* G1 = (const float*)d_in[2];
    const float* G2 = (const float*)d_in[3];
    const float* G3 = (const float*)d_in[4];
    float* out = (float*)d_out;

    int B = in_sizes[0] / 4;   // X is [B,4]
    int block = 256;
    int grid = (B + block * ROWS - 1) / (block * ROWS);
    int S = grid * block;
    tt_poly_kernel<<<grid, block, 0, stream>>>(X, G0, G1, G2, G3, out, B, S);
}